// Round 1
// baseline (542.852 us; speedup 1.0000x reference)
//
#include <hip/hip_runtime.h>
#include <math.h>

#define BS 16
#define QN 900
#define NC 92
#define TN 100
#define NQ (BS * QN)        // 14400
#define NT (BS * TN)        // 1600
#define C_ELEMS ((size_t)NQ * NT)  // 23,040,000

// ---------------------------------------------------------------------------
// cost of matching pred q (cxcywh box pb, class prob p_cls) with target (xyxy tb)
// mirrors reference arithmetic order as closely as practical (fp32 throughout)
// ---------------------------------------------------------------------------
__device__ __forceinline__ float cost_entry(float4 pb, float p_cls, float4 tb) {
    // target xyxy -> cxcywh (reference box_xyxy_to_cxcywh)
    float tcx = (tb.x + tb.z) * 0.5f;
    float tcy = (tb.y + tb.w) * 0.5f;
    float tw  = tb.z - tb.x;
    float th  = tb.w - tb.y;
    // L1 cost in cxcywh space
    float cb = fabsf(pb.x - tcx) + fabsf(pb.y - tcy);
    cb += fabsf(pb.z - tw);
    cb += fabsf(pb.w - th);
    // pred cxcywh -> xyxy (reference box_cxcywh_to_xyxy: c - s/2, c + s/2)
    float ax0 = pb.x - pb.z * 0.5f;
    float ay0 = pb.y - pb.w * 0.5f;
    float ax1 = pb.x + pb.z * 0.5f;
    float ay1 = pb.y + pb.w * 0.5f;
    float area_a = (ax1 - ax0) * (ay1 - ay0);
    float area_b = (tb.z - tb.x) * (tb.w - tb.y);
    float ltx = fmaxf(ax0, tb.x), lty = fmaxf(ay0, tb.y);
    float rbx = fminf(ax1, tb.z), rby = fminf(ay1, tb.w);
    float iw = fmaxf(rbx - ltx, 0.0f), ih = fmaxf(rby - lty, 0.0f);
    float inter = iw * ih;
    float uni = area_a + area_b - inter;
    float iou = inter / uni;
    float cx0 = fminf(ax0, tb.x), cy0 = fminf(ay0, tb.y);
    float cx1 = fmaxf(ax1, tb.z), cy1 = fmaxf(ay1, tb.w);
    float cw = fmaxf(cx1 - cx0, 0.0f), chh = fmaxf(cy1 - cy0, 0.0f);
    float area_c = cw * chh;
    float giou = iou - (area_c - uni) / area_c;
    // C = 5*cost_bbox + 1*cost_class + 2*cost_giou; cost_class = -prob, cost_giou = -giou
    return (5.0f * cb - p_cls) + 2.0f * (-giou);
}

// ---------------------------------------------------------------------------
// Kernel A: per-query softmax -> prob[NQ][NC]. One wave per query.
// ---------------------------------------------------------------------------
__global__ void softmax_kernel(const float* __restrict__ logits, float* __restrict__ prob) {
    int wid = threadIdx.x >> 6;
    int lane = threadIdx.x & 63;
    int q = blockIdx.x * 4 + wid;
    if (q >= NQ) return;
    const float* row = logits + (size_t)q * NC;
    float x0 = (lane < NC) ? row[lane] : -INFINITY;
    float x1 = (lane + 64 < NC) ? row[lane + 64] : -INFINITY;
    float m = fmaxf(x0, x1);
    for (int off = 32; off; off >>= 1) m = fmaxf(m, __shfl_down(m, off));
    m = __shfl(m, 0);
    float e0 = (lane < NC) ? expf(x0 - m) : 0.0f;
    float e1 = (lane + 64 < NC) ? expf(x1 - m) : 0.0f;
    float s = e0 + e1;
    for (int off = 32; off; off >>= 1) s += __shfl_down(s, off);
    s = __shfl(s, 0);
    if (lane < NC) prob[(size_t)q * NC + lane] = e0 / s;
    if (lane + 64 < NC) prob[(size_t)q * NC + lane + 64] = e1 / s;
}

// ---------------------------------------------------------------------------
// Kernel B1: full cost matrix C[NQ][NT] into d_out. Wave per query, lanes over t.
// ---------------------------------------------------------------------------
__global__ void cost_kernel(const float* __restrict__ prob,
                            const float4* __restrict__ pred_boxes,
                            const int* __restrict__ tgt_ids,
                            const float4* __restrict__ tgt_bbox,
                            float* __restrict__ C) {
    int wid = threadIdx.x >> 6;
    int lane = threadIdx.x & 63;
    int q = blockIdx.x * 4 + wid;
    if (q >= NQ) return;
    float4 pb = pred_boxes[q];
    const float* prow = prob + (size_t)q * NC;
    float* crow = C + (size_t)q * NT;
    for (int t = lane; t < NT; t += 64) {
        float4 tb = tgt_bbox[t];
        int id = tgt_ids[t];
        crow[t] = cost_entry(pb, prow[id], tb);
    }
}

// ---------------------------------------------------------------------------
// Kernel B2: transposed per-batch diagonal blocks cost_t[b][tt][q] (coalesced in q)
// for the LSA's row reads. Recomputes instead of reading C (cheap).
// ---------------------------------------------------------------------------
__global__ void cost_t_kernel(const float* __restrict__ prob,
                              const float4* __restrict__ pred_boxes,
                              const int* __restrict__ tgt_ids,
                              const float4* __restrict__ tgt_bbox,
                              float* __restrict__ cost_t) {
    int b = blockIdx.x / TN;
    int tt = blockIdx.x % TN;
    int tg = b * TN + tt;
    float4 tb = tgt_bbox[tg];
    int id = tgt_ids[tg];
    float* row = cost_t + ((size_t)b * TN + tt) * QN;
    for (int qq = threadIdx.x; qq < QN; qq += 256) {
        int qg = b * QN + qq;
        row[qq] = cost_entry(pred_boxes[qg], prob[(size_t)qg * NC + id], tb);
    }
}

// ---------------------------------------------------------------------------
// Kernel C: Hungarian (shortest augmenting path, exact mirror of reference _lsa)
// on the transposed block: n=100 rows (targets), m=900 cols (preds).
// One block per batch; 256 threads parallelize the column scan / dual update.
// ---------------------------------------------------------------------------
__global__ __launch_bounds__(256) void lsa_kernel(const float* __restrict__ cost_t,
                                                  float* __restrict__ out) {
    int b = blockIdx.x;
    const float* cst = cost_t + (size_t)b * TN * QN;  // [tt][q]
    __shared__ float v[QN + 1];
    __shared__ float minv[QN + 1];
    __shared__ float u[TN + 1];
    __shared__ int p[QN + 1];
    __shared__ int way[QN + 1];
    __shared__ unsigned char used[QN + 1];
    __shared__ float redv[4];
    __shared__ int redi[4];
    __shared__ int s_i0, s_j0, s_done;
    __shared__ float s_delta;
    int tid = threadIdx.x;

    for (int j = tid; j <= QN; j += 256) { v[j] = 0.0f; p[j] = 0; way[j] = 0; }
    if (tid <= TN) u[tid] = 0.0f;
    __syncthreads();

    for (int i = 1; i <= TN; ++i) {
        if (tid == 0) { p[0] = i; s_j0 = 0; }
        for (int j = tid; j <= QN; j += 256) { minv[j] = INFINITY; used[j] = 0; }
        __syncthreads();
        while (true) {
            if (tid == 0) { int j0 = s_j0; used[j0] = 1; s_i0 = p[j0]; }
            __syncthreads();                       // B1
            int j0 = s_j0;
            int i0 = s_i0;
            float ui0 = u[i0];
            const float* crow = cst + (size_t)(i0 - 1) * QN;
            float lv = INFINITY;
            int li = 0x7fffffff;
            for (int j = 1 + tid; j <= QN; j += 256) {
                if (!used[j]) {
                    float cur = crow[j - 1] - ui0 - v[j];
                    if (cur < minv[j]) { minv[j] = cur; way[j] = j0; }
                    float m = minv[j];
                    if (m < lv) { lv = m; li = j; }   // per-thread j ascending: first-min kept
                }
            }
            // lexicographic (value, index) min across the wave, then across 4 waves
            for (int off = 32; off; off >>= 1) {
                float ov = __shfl_down(lv, off);
                int oi = __shfl_down(li, off);
                if (ov < lv || (ov == lv && oi < li)) { lv = ov; li = oi; }
            }
            int wv = tid >> 6;
            if ((tid & 63) == 0) { redv[wv] = lv; redi[wv] = li; }
            __syncthreads();                       // B2
            if (tid == 0) {
                float dv = redv[0]; int di = redi[0];
                for (int w = 1; w < 4; ++w) {
                    float ov = redv[w]; int oi = redi[w];
                    if (ov < dv || (ov == dv && oi < di)) { dv = ov; di = oi; }
                }
                s_delta = dv;
                s_done = (p[di] == 0);
                s_j0 = di;
            }
            __syncthreads();                       // B3
            float delta = s_delta;
            for (int j = tid; j <= QN; j += 256) {
                if (used[j]) { v[j] -= delta; u[p[j]] += delta; }
                else minv[j] -= delta;
            }
            __syncthreads();                       // B4
            if (s_done) break;
        }
        if (tid == 0) {
            int j0 = s_j0;
            while (j0) { int j1 = way[j0]; p[j0] = p[j1]; j0 = j1; }
        }
        __syncthreads();
    }
    // emit rows/cols: matched columns in ascending j == sorted by pred index
    if (tid == 0) {
        float* rows = out + C_ELEMS + (size_t)b * TN;
        float* cols = out + C_ELEMS + (size_t)BS * TN + (size_t)b * TN;
        int k = 0;
        for (int j = 1; j <= QN; ++j) {
            if (p[j] > 0) { rows[k] = (float)(j - 1); cols[k] = (float)(p[j] - 1); ++k; }
        }
    }
}

extern "C" void kernel_launch(void* const* d_in, const int* in_sizes, int n_in,
                              void* d_out, int out_size, void* d_ws, size_t ws_size,
                              hipStream_t stream) {
    const float* logits = (const float*)d_in[0];        // (16,900,92)
    const float4* pboxes = (const float4*)d_in[1];      // (16,900,4) cxcywh
    const int* tids = (const int*)d_in[2];              // (1600,)
    const float4* tbox = (const float4*)d_in[3];        // (1600,4) xyxy
    float* out = (float*)d_out;

    float* prob = (float*)d_ws;                         // NQ*NC floats = 5.3 MB
    float* cost_t = prob + (size_t)NQ * NC;             // 16*100*900 floats = 5.76 MB

    softmax_kernel<<<NQ / 4, 256, 0, stream>>>(logits, prob);
    cost_kernel<<<NQ / 4, 256, 0, stream>>>(prob, pboxes, tids, tbox, out);
    cost_t_kernel<<<BS * TN, 256, 0, stream>>>(prob, pboxes, tids, tbox, cost_t);
    lsa_kernel<<<BS, 256, 0, stream>>>(cost_t, out);
}

// Round 2
// 291.808 us; speedup vs baseline: 1.8603x; 1.8603x over previous
//
#include <hip/hip_runtime.h>
#include <math.h>

#define BS 16
#define QN 900
#define NC 92
#define TN 100
#define NQ (BS * QN)        // 14400
#define NT (BS * TN)        // 1600
#define C_ELEMS ((size_t)NQ * NT)  // 23,040,000
#define NK 15               // ceil(900/64) columns owned per lane

// ---------------------------------------------------------------------------
// cost of matching pred (cxcywh pb, class prob p_cls) with target (xyxy tb)
// ---------------------------------------------------------------------------
__device__ __forceinline__ float cost_entry(float4 pb, float p_cls, float4 tb) {
    float tcx = (tb.x + tb.z) * 0.5f;
    float tcy = (tb.y + tb.w) * 0.5f;
    float tw  = tb.z - tb.x;
    float th  = tb.w - tb.y;
    float cb = fabsf(pb.x - tcx) + fabsf(pb.y - tcy);
    cb += fabsf(pb.z - tw);
    cb += fabsf(pb.w - th);
    float ax0 = pb.x - pb.z * 0.5f;
    float ay0 = pb.y - pb.w * 0.5f;
    float ax1 = pb.x + pb.z * 0.5f;
    float ay1 = pb.y + pb.w * 0.5f;
    float area_a = (ax1 - ax0) * (ay1 - ay0);
    float area_b = (tb.z - tb.x) * (tb.w - tb.y);
    float ltx = fmaxf(ax0, tb.x), lty = fmaxf(ay0, tb.y);
    float rbx = fminf(ax1, tb.z), rby = fminf(ay1, tb.w);
    float iw = fmaxf(rbx - ltx, 0.0f), ih = fmaxf(rby - lty, 0.0f);
    float inter = iw * ih;
    float uni = area_a + area_b - inter;
    float iou = inter / uni;
    float cx0 = fminf(ax0, tb.x), cy0 = fminf(ay0, tb.y);
    float cx1 = fmaxf(ax1, tb.z), cy1 = fmaxf(ay1, tb.w);
    float cw = fmaxf(cx1 - cx0, 0.0f), chh = fmaxf(cy1 - cy0, 0.0f);
    float area_c = cw * chh;
    float giou = iou - (area_c - uni) / area_c;
    return (5.0f * cb - p_cls) + 2.0f * (-giou);
}

// ---------------------------------------------------------------------------
// Kernel A: fused softmax + full cost matrix. One wave per query.
// prob row staged in LDS for the class-id gather; also written to ws for B2.
// ---------------------------------------------------------------------------
__global__ __launch_bounds__(256) void softmax_cost_kernel(
        const float* __restrict__ logits,
        const float4* __restrict__ pboxes,
        const int* __restrict__ tids,
        const float4* __restrict__ tbox,
        float* __restrict__ C,
        float* __restrict__ prob) {
    __shared__ float shp[4][NC];
    int wid = threadIdx.x >> 6;
    int lane = threadIdx.x & 63;
    int q = blockIdx.x * 4 + wid;
    const float* row = logits + (size_t)q * NC;
    float x0 = (lane < NC) ? row[lane] : -INFINITY;
    float x1 = (lane + 64 < NC) ? row[lane + 64] : -INFINITY;
    float m = fmaxf(x0, x1);
    for (int off = 32; off; off >>= 1) m = fmaxf(m, __shfl_xor(m, off));
    float e0 = (lane < NC) ? expf(x0 - m) : 0.0f;
    float e1 = (lane + 64 < NC) ? expf(x1 - m) : 0.0f;
    float s = e0 + e1;
    for (int off = 32; off; off >>= 1) s += __shfl_xor(s, off);
    if (lane < NC) { float p0 = e0 / s; shp[wid][lane] = p0; prob[(size_t)q * NC + lane] = p0; }
    if (lane + 64 < NC) { float p1 = e1 / s; shp[wid][lane + 64] = p1; prob[(size_t)q * NC + lane + 64] = p1; }
    __syncthreads();
    float4 pb = pboxes[q];
    float* crow = C + (size_t)q * NT;
    for (int t = lane; t < NT; t += 64) {
        crow[t] = cost_entry(pb, shp[wid][tids[t]], tbox[t]);
    }
}

// ---------------------------------------------------------------------------
// Kernel B2: transposed diagonal blocks cost_t[b][tt][q] + per-row (min, argmin)
// for the JV greedy initialization. First-index tie-break (matches np.argmin).
// ---------------------------------------------------------------------------
__global__ __launch_bounds__(256) void cost_t_kernel(
        const float* __restrict__ prob,
        const float4* __restrict__ pboxes,
        const int* __restrict__ tids,
        const float4* __restrict__ tbox,
        float* __restrict__ cost_t,
        float* __restrict__ rowmin,
        int* __restrict__ rowarg) {
    __shared__ float redv[4];
    __shared__ int redi[4];
    int b = blockIdx.x / TN;
    int tt = blockIdx.x % TN;
    int tg = b * TN + tt;
    float4 tb = tbox[tg];
    int id = tids[tg];
    float* rowp = cost_t + ((size_t)b * TN + tt) * QN;
    float lmin = INFINITY; int larg = 0x7fffffff;
    for (int qq = threadIdx.x; qq < QN; qq += 256) {
        int qg = b * QN + qq;
        float c = cost_entry(pboxes[qg], prob[(size_t)qg * NC + id], tb);
        rowp[qq] = c;
        if (c < lmin) { lmin = c; larg = qq; }  // qq ascending per thread
    }
    int lane = threadIdx.x & 63, wv = threadIdx.x >> 6;
    for (int off = 32; off; off >>= 1) {
        float ov = __shfl_xor(lmin, off); int oi = __shfl_xor(larg, off);
        if (ov < lmin || (ov == lmin && oi < larg)) { lmin = ov; larg = oi; }
    }
    if (lane == 0) { redv[wv] = lmin; redi[wv] = larg; }
    __syncthreads();
    if (threadIdx.x == 0) {
        float dv = redv[0]; int di = redi[0];
        for (int w = 1; w < 4; ++w) {
            float ov = redv[w]; int oi = redi[w];
            if (ov < dv || (ov == dv && oi < di)) { dv = ov; di = oi; }
        }
        rowmin[tg] = dv;
        rowarg[tg] = di;
    }
}

// ---------------------------------------------------------------------------
// Kernel C: exact Hungarian with JV init. One 64-lane wave per batch.
// Column-state (v, minv, used, p-of-used) in registers: 15 cols per lane,
// col c owned by lane c%64, slot k=c/64. u/p/way in LDS. Argmin via shfl_xor.
// ---------------------------------------------------------------------------
__global__ __launch_bounds__(64) void lsa_kernel(
        const float* __restrict__ cost_t,
        const float* __restrict__ rowmin,
        const int* __restrict__ rowarg,
        float* __restrict__ out) {
    int b = blockIdx.x;
    int lane = threadIdx.x;
    const float* cst = cost_t + (size_t)b * TN * QN;
    __shared__ float u_s[TN + 1];
    __shared__ int p_s[QN + 1];
    __shared__ int way_s[QN + 1];
    __shared__ int unm[TN];
    __shared__ int s_nunm;
    float v_r[NK], minv_r[NK];
    int pj_r[NK];
    unsigned used_mask;

    #pragma unroll
    for (int k = 0; k < NK; ++k) v_r[k] = 0.0f;
    for (int j = lane; j <= QN; j += 64) p_s[j] = 0;
    if (lane == 0) u_s[0] = 0.0f;
    for (int i = lane; i < TN; i += 64) u_s[i + 1] = rowmin[b * TN + i];
    __syncthreads();

    // JV greedy: u[i]=rowmin -> (i, argmin_i) has reduced cost exactly 0.
    if (lane == 0) {
        int cnt = 0;
        for (int i = 1; i <= TN; ++i) {
            int jstar = rowarg[b * TN + i - 1] + 1;
            if (p_s[jstar] == 0) p_s[jstar] = i;
            else unm[cnt++] = i;
        }
        s_nunm = cnt;
    }
    __syncthreads();
    int nunm = s_nunm;

    for (int ui = 0; ui < nunm; ++ui) {
        int i_cur = unm[ui];
        if (lane == 0) p_s[0] = i_cur;
        used_mask = 0;
        #pragma unroll
        for (int k = 0; k < NK; ++k) minv_r[k] = INFINITY;
        int j0 = 0;
        __syncthreads();
        while (true) {
            int i0;
            if (j0 == 0) {
                i0 = i_cur;
            } else {
                i0 = p_s[j0];
                int c0 = j0 - 1;
                if ((c0 & 63) == lane) { int k0 = c0 >> 6; used_mask |= 1u << k0; pj_r[k0] = i0; }
            }
            float ui0 = u_s[i0];
            const float* crow = cst + (size_t)(i0 - 1) * QN;
            float lv = INFINITY; int li = 0x7fffffff;
            #pragma unroll
            for (int k = 0; k < NK; ++k) {
                int c = lane + (k << 6);
                if (c < QN && !(used_mask & (1u << k))) {
                    float cur = crow[c] - ui0 - v_r[k];
                    if (cur < minv_r[k]) { minv_r[k] = cur; way_s[c + 1] = j0; }
                    float mm = minv_r[k];
                    if (mm < lv) { lv = mm; li = c + 1; }  // k asc => c asc: first-min kept
                }
            }
            // global lexicographic (value, index) min -> identical in all lanes
            for (int off = 1; off < 64; off <<= 1) {
                float ov = __shfl_xor(lv, off);
                int oi = __shfl_xor(li, off);
                if (ov < lv || (ov == lv && oi < li)) { lv = ov; li = oi; }
            }
            float delta = lv;
            int j1 = li;
            #pragma unroll
            for (int k = 0; k < NK; ++k) {
                int c = lane + (k << 6);
                if (c < QN) {
                    if (used_mask & (1u << k)) { v_r[k] -= delta; u_s[pj_r[k]] += delta; }
                    else minv_r[k] -= delta;
                }
            }
            if (lane == 0) u_s[i_cur] += delta;  // virtual column 0: p[0] = i_cur
            int pj1 = p_s[j1];
            j0 = j1;
            __syncthreads();  // u_s/way_s writes visible before next read
            if (pj1 == 0) break;
        }
        if (lane == 0) {
            int jj = j0;
            while (jj) { int jn = way_s[jj]; p_s[jj] = p_s[jn]; jj = jn; }
        }
        __syncthreads();
    }

    // emit: matched columns ascending j == preds ascending (ballot ranking)
    float* rows = out + C_ELEMS + (size_t)b * TN;
    float* cols = out + C_ELEMS + (size_t)BS * TN + (size_t)b * TN;
    int base = 0;
    #pragma unroll
    for (int k = 0; k < NK; ++k) {
        int c = lane + (k << 6);
        int pv = (c < QN) ? p_s[c + 1] : 0;
        unsigned long long mask = __ballot(pv > 0);
        if (pv > 0) {
            int rank = base + __popcll(mask & ((1ull << lane) - 1ull));
            rows[rank] = (float)c;
            cols[rank] = (float)(pv - 1);
        }
        base += __popcll(mask);
    }
}

extern "C" void kernel_launch(void* const* d_in, const int* in_sizes, int n_in,
                              void* d_out, int out_size, void* d_ws, size_t ws_size,
                              hipStream_t stream) {
    const float* logits = (const float*)d_in[0];        // (16,900,92)
    const float4* pboxes = (const float4*)d_in[1];      // (16,900,4) cxcywh
    const int* tids = (const int*)d_in[2];              // (1600,)
    const float4* tbox = (const float4*)d_in[3];        // (1600,4) xyxy
    float* out = (float*)d_out;

    float* prob = (float*)d_ws;                         // NQ*NC floats
    float* cost_t = prob + (size_t)NQ * NC;             // BS*TN*QN floats
    float* rowmin = cost_t + (size_t)BS * TN * QN;      // NT floats
    int* rowarg = (int*)(rowmin + NT);                  // NT ints

    softmax_cost_kernel<<<NQ / 4, 256, 0, stream>>>(logits, pboxes, tids, tbox, out, prob);
    cost_t_kernel<<<BS * TN, 256, 0, stream>>>(prob, pboxes, tids, tbox, cost_t, rowmin, rowarg);
    lsa_kernel<<<BS, 64, 0, stream>>>(cost_t, rowmin, rowarg, out);
}

// Round 3
// 223.275 us; speedup vs baseline: 2.4313x; 1.3069x over previous
//
#include <hip/hip_runtime.h>
#include <math.h>

#define BS 16
#define QN 900
#define NC 92
#define TN 100
#define NQ (BS * QN)        // 14400
#define NT (BS * TN)        // 1600
#define C_ELEMS ((size_t)NQ * NT)  // 23,040,000
#define NK 15               // ceil(900/64) columns owned per lane

// ---------------------------------------------------------------------------
// cost of matching pred (cxcywh pb, class prob p_cls) with target (xyxy tb)
// ---------------------------------------------------------------------------
__device__ __forceinline__ float cost_entry(float4 pb, float p_cls, float4 tb) {
    float tcx = (tb.x + tb.z) * 0.5f;
    float tcy = (tb.y + tb.w) * 0.5f;
    float tw  = tb.z - tb.x;
    float th  = tb.w - tb.y;
    float cb = fabsf(pb.x - tcx) + fabsf(pb.y - tcy);
    cb += fabsf(pb.z - tw);
    cb += fabsf(pb.w - th);
    float ax0 = pb.x - pb.z * 0.5f;
    float ay0 = pb.y - pb.w * 0.5f;
    float ax1 = pb.x + pb.z * 0.5f;
    float ay1 = pb.y + pb.w * 0.5f;
    float area_a = (ax1 - ax0) * (ay1 - ay0);
    float area_b = (tb.z - tb.x) * (tb.w - tb.y);
    float ltx = fmaxf(ax0, tb.x), lty = fmaxf(ay0, tb.y);
    float rbx = fminf(ax1, tb.z), rby = fminf(ay1, tb.w);
    float iw = fmaxf(rbx - ltx, 0.0f), ih = fmaxf(rby - lty, 0.0f);
    float inter = iw * ih;
    float uni = area_a + area_b - inter;
    float iou = inter / uni;
    float cx0 = fminf(ax0, tb.x), cy0 = fminf(ay0, tb.y);
    float cx1 = fmaxf(ax1, tb.z), cy1 = fmaxf(ay1, tb.w);
    float cw = fmaxf(cx1 - cx0, 0.0f), chh = fmaxf(cy1 - cy0, 0.0f);
    float area_c = cw * chh;
    float giou = iou - (area_c - uni) / area_c;
    return (5.0f * cb - p_cls) + 2.0f * (-giou);
}

// lexicographic (value, index) min across 64 lanes; result in all lanes
__device__ __forceinline__ void wave_argmin(float& lv, int& li) {
    for (int off = 1; off < 64; off <<= 1) {
        float ov = __shfl_xor(lv, off);
        int oi = __shfl_xor(li, off);
        if (ov < lv || (ov == lv && oi < li)) { lv = ov; li = oi; }
    }
}

// ---------------------------------------------------------------------------
// Kernel A: fused softmax + full cost matrix C (float4 stores). Wave per query.
// ---------------------------------------------------------------------------
__global__ __launch_bounds__(256) void softmax_cost_kernel(
        const float* __restrict__ logits,
        const float4* __restrict__ pboxes,
        const int4* __restrict__ tids4,
        const float4* __restrict__ tbox,
        float* __restrict__ C) {
    __shared__ float shp[4][NC];
    int wid = threadIdx.x >> 6;
    int lane = threadIdx.x & 63;
    int q = blockIdx.x * 4 + wid;
    const float* row = logits + (size_t)q * NC;
    float x0 = (lane < NC) ? row[lane] : -INFINITY;
    float x1 = (lane + 64 < NC) ? row[lane + 64] : -INFINITY;
    float m = fmaxf(x0, x1);
    for (int off = 32; off; off >>= 1) m = fmaxf(m, __shfl_xor(m, off));
    float e0 = (lane < NC) ? expf(x0 - m) : 0.0f;
    float e1 = (lane + 64 < NC) ? expf(x1 - m) : 0.0f;
    float s = e0 + e1;
    for (int off = 32; off; off >>= 1) s += __shfl_xor(s, off);
    if (lane < NC) shp[wid][lane] = e0 / s;
    if (lane + 64 < NC) shp[wid][lane + 64] = e1 / s;
    __syncthreads();
    float4 pb = pboxes[q];
    float4* crow4 = (float4*)(C + (size_t)q * NT);
    for (int t4 = lane; t4 < NT / 4; t4 += 64) {
        int4 id = tids4[t4];
        int t = t4 * 4;
        float4 r;
        r.x = cost_entry(pb, shp[wid][id.x], tbox[t]);
        r.y = cost_entry(pb, shp[wid][id.y], tbox[t + 1]);
        r.z = cost_entry(pb, shp[wid][id.z], tbox[t + 2]);
        r.w = cost_entry(pb, shp[wid][id.w], tbox[t + 3]);
        crow4[t4] = r;
    }
}

// ---------------------------------------------------------------------------
// Kernel B: transpose C's per-batch diagonal 900x100 block -> cost_t[b][tt][q].
// LDS 64x64 tiles, coalesced both directions, +1 pad kills bank conflicts.
// ---------------------------------------------------------------------------
__global__ __launch_bounds__(256) void diag_transpose_kernel(
        const float* __restrict__ C, float* __restrict__ cost_t) {
    __shared__ float tile[64][65];
    int b = blockIdx.x;
    int q0 = blockIdx.y * 64;   // 15 tiles (last is 4 wide)
    int t0 = blockIdx.z * 64;   // 2 tiles (second is 36 wide)
    int tx = threadIdx.x & 63;
    int ty = threadIdx.x >> 6;
    for (int r = ty; r < 64; r += 4) {
        int q = q0 + r, t = t0 + tx;
        if (q < QN && t < TN)
            tile[r][tx] = C[(size_t)(b * QN + q) * NT + b * TN + t];
    }
    __syncthreads();
    for (int r = ty; r < 64; r += 4) {
        int t = t0 + r, q = q0 + tx;
        if (q < QN && t < TN)
            cost_t[(size_t)(b * TN + t) * QN + q] = tile[tx][r];
    }
}

// ---------------------------------------------------------------------------
// Kernel B2: per-row (min, argmin) of cost_t. One wave per (b,tt).
// ---------------------------------------------------------------------------
__global__ __launch_bounds__(64) void rowmin_kernel(
        const float* __restrict__ cost_t,
        float* __restrict__ rowmin, int* __restrict__ rowarg) {
    int tg = blockIdx.x;
    int lane = threadIdx.x;
    const float* row = cost_t + (size_t)tg * QN;
    float lv = INFINITY; int li = 0x7fffffff;
    #pragma unroll
    for (int k = 0; k < NK; ++k) {
        int c = lane + (k << 6);
        if (c < QN) {
            float v = row[c];
            if (v < lv) { lv = v; li = c; }  // k asc => c asc: first-min kept
        }
    }
    wave_argmin(lv, li);
    if (lane == 0) { rowmin[tg] = lv; rowarg[tg] = li; }
}

// ---------------------------------------------------------------------------
// Kernel C: exact Hungarian, JV greedy init, software-pipelined Dijkstra.
// One 64-lane wave per batch. Current cost row held in registers; next row
// prefetched right after the argmin so its latency overlaps the dual update.
// ---------------------------------------------------------------------------
__global__ __launch_bounds__(64) void lsa_kernel(
        const float* __restrict__ cost_t,
        const float* __restrict__ rowmin,
        const int* __restrict__ rowarg,
        float* __restrict__ out) {
    int b = blockIdx.x;
    int lane = threadIdx.x;
    const float* cst = cost_t + (size_t)b * TN * QN;
    __shared__ float u_s[TN + 1];
    __shared__ int p_s[QN + 1];
    __shared__ int way_s[QN + 1];
    __shared__ int unm[TN];
    float v_r[NK], minv_r[NK], rowc[NK], rown[NK];
    int pj_r[NK];
    unsigned used_mask;

    #pragma unroll
    for (int k = 0; k < NK; ++k) v_r[k] = 0.0f;
    for (int j = lane; j <= QN; j += 64) p_s[j] = 0x7fffffff;  // sentinel: free
    if (lane == 0) u_s[0] = 0.0f;
    int jst0 = 0, jst1 = 0;
    for (int i = lane; i < TN; i += 64) {
        u_s[i + 1] = rowmin[b * TN + i];
        int js = rowarg[b * TN + i] + 1;
        if (i < 64) jst0 = js; else jst1 = js;
    }
    __syncthreads();
    // parallel greedy: column j gets min row index among rows whose argmin is j
    if (lane < TN) atomicMin(&p_s[jst0], lane + 1);
    if (lane + 64 < TN) atomicMin(&p_s[jst1], lane + 64 + 1);
    __syncthreads();
    // build unmatched-row list (ascending), clear sentinels
    int nunm = 0;
    {
        bool um0 = (lane < TN) && (p_s[jst0] != lane + 1);
        unsigned long long m0 = __ballot(um0);
        if (um0) unm[__popcll(m0 & ((1ull << lane) - 1ull))] = lane + 1;
        nunm = __popcll(m0);
        bool um1 = (lane + 64 < TN) && (p_s[jst1] != lane + 64 + 1);
        unsigned long long m1 = __ballot(um1);
        if (um1) unm[nunm + __popcll(m1 & ((1ull << lane) - 1ull))] = lane + 64 + 1;
        nunm += __popcll(m1);
    }
    __syncthreads();
    for (int j = lane; j <= QN; j += 64) if (p_s[j] == 0x7fffffff) p_s[j] = 0;
    __syncthreads();

    for (int ui = 0; ui < nunm; ++ui) {
        int i_cur = unm[ui];
        if (lane == 0) p_s[0] = i_cur;
        used_mask = 0;
        #pragma unroll
        for (int k = 0; k < NK; ++k) minv_r[k] = INFINITY;
        int i0 = i_cur, j0 = 0;
        {
            const float* crow = cst + (size_t)(i0 - 1) * QN;
            #pragma unroll
            for (int k = 0; k < NK; ++k) {
                int c = lane + (k << 6);
                rowc[k] = (c < QN) ? crow[c] : 0.0f;
            }
        }
        while (true) {
            float ui0 = u_s[i0];
            float lv = INFINITY; int li = 0x7fffffff;
            #pragma unroll
            for (int k = 0; k < NK; ++k) {
                int c = lane + (k << 6);
                if (c < QN && !(used_mask & (1u << k))) {
                    float cur = rowc[k] - ui0 - v_r[k];
                    if (cur < minv_r[k]) { minv_r[k] = cur; way_s[c + 1] = j0; }
                    float mm = minv_r[k];
                    if (mm < lv) { lv = mm; li = c + 1; }  // c asc: first-min kept
                }
            }
            wave_argmin(lv, li);
            float delta = lv;
            int j1 = li;
            int pj1 = p_s[j1];
            // prefetch next row NOW; latency overlaps the dual update below
            {
                int irow = (pj1 == 0) ? i0 : pj1;
                const float* crow = cst + (size_t)(irow - 1) * QN;
                #pragma unroll
                for (int k = 0; k < NK; ++k) {
                    int c = lane + (k << 6);
                    rown[k] = (c < QN) ? crow[c] : 0.0f;
                }
            }
            // dual update over current used set (j1 NOT yet marked — ref order)
            #pragma unroll
            for (int k = 0; k < NK; ++k) {
                int c = lane + (k << 6);
                if (c < QN) {
                    if (used_mask & (1u << k)) { v_r[k] -= delta; u_s[pj_r[k]] += delta; }
                    else minv_r[k] -= delta;
                }
            }
            if (lane == 0) u_s[i_cur] += delta;  // virtual column 0
            // mark j1 used for subsequent steps
            {
                int c0 = j1 - 1;
                if ((c0 & 63) == lane) { int k0 = c0 >> 6; used_mask |= 1u << k0; pj_r[k0] = pj1; }
            }
            __syncthreads();  // u_s / way_s visible before next scan or augment
            j0 = j1;
            if (pj1 == 0) break;
            i0 = pj1;
            #pragma unroll
            for (int k = 0; k < NK; ++k) rowc[k] = rown[k];
        }
        if (lane == 0) {
            int jj = j0;
            while (jj) { int jn = way_s[jj]; p_s[jj] = p_s[jn]; jj = jn; }
        }
        __syncthreads();
    }

    // emit: matched columns ascending j == preds ascending (ballot ranking)
    float* rows = out + C_ELEMS + (size_t)b * TN;
    float* cols = out + C_ELEMS + (size_t)BS * TN + (size_t)b * TN;
    int base = 0;
    #pragma unroll
    for (int k = 0; k < NK; ++k) {
        int c = lane + (k << 6);
        int pv = (c < QN) ? p_s[c + 1] : 0;
        unsigned long long mask = __ballot(pv > 0);
        if (pv > 0) {
            int rank = base + __popcll(mask & ((1ull << lane) - 1ull));
            rows[rank] = (float)c;
            cols[rank] = (float)(pv - 1);
        }
        base += __popcll(mask);
    }
}

extern "C" void kernel_launch(void* const* d_in, const int* in_sizes, int n_in,
                              void* d_out, int out_size, void* d_ws, size_t ws_size,
                              hipStream_t stream) {
    const float* logits = (const float*)d_in[0];        // (16,900,92)
    const float4* pboxes = (const float4*)d_in[1];      // (16,900,4) cxcywh
    const int* tids = (const int*)d_in[2];              // (1600,)
    const float4* tbox = (const float4*)d_in[3];        // (1600,4) xyxy
    float* out = (float*)d_out;

    float* cost_t = (float*)d_ws;                       // BS*TN*QN floats (5.76 MB)
    float* rowmin = cost_t + (size_t)BS * TN * QN;      // NT floats
    int* rowarg = (int*)(rowmin + NT);                  // NT ints

    softmax_cost_kernel<<<NQ / 4, 256, 0, stream>>>(logits, pboxes, (const int4*)tids, tbox, out);
    diag_transpose_kernel<<<dim3(BS, 15, 2), 256, 0, stream>>>(out, cost_t);
    rowmin_kernel<<<NT, 64, 0, stream>>>(cost_t, rowmin, rowarg);
    lsa_kernel<<<BS, 64, 0, stream>>>(cost_t, rowmin, rowarg, out);
}